// Round 6
// baseline (813.094 us; speedup 1.0000x reference)
//
#include <hip/hip_runtime.h>
#include <cfloat>

#define NROWS  32768
#define NCODES 8192
#define DDIM   256
#define CT     128              // codes per tile
#define NTILE  (NCODES / CT)    // 64
#define BK     32               // k per chunk (one 16x16x32 MFMA)
#define NCH    (DDIM / BK)      // 8 chunks per tile
#define NCHUNKS (NTILE * NCH)   // 512 linear chunks

typedef __attribute__((ext_vector_type(8))) __bf16 bf16x8;
typedef __attribute__((ext_vector_type(4))) float  f32x4;

// ---- kernel A: codebook fp32 -> bf16 + fused esq (z handled inside vq_mfma) ----
__global__ __launch_bounds__(256)
void cvt_cb(const float* __restrict__ cb, __bf16* __restrict__ cbb,
            float* __restrict__ esq) {
    const size_t i = (size_t)(blockIdx.x * 256 + threadIdx.x) * 8;
    const float4 f0 = *(const float4*)(cb + i);
    const float4 f1 = *(const float4*)(cb + i + 4);
    bf16x8 v;
    v[0] = (__bf16)f0.x; v[1] = (__bf16)f0.y; v[2] = (__bf16)f0.z; v[3] = (__bf16)f0.w;
    v[4] = (__bf16)f1.x; v[5] = (__bf16)f1.y; v[6] = (__bf16)f1.z; v[7] = (__bf16)f1.w;
    *(bf16x8*)(cbb + i) = v;
    float s = f0.x * f0.x + f0.y * f0.y + f0.z * f0.z + f0.w * f0.w
            + f1.x * f1.x + f1.y * f1.y + f1.z * f1.z + f1.w * f1.w;
    for (int o = 16; o > 0; o >>= 1) s += __shfl_down(s, o, 32);
    if ((threadIdx.x & 31) == 0) esq[i >> 8] = s;
}

// ---- kernel B: A-in-registers, B global->VGPR streamed, NO LDS / NO BARRIERS ----
// Block: 512 thr / 8 waves (4 row-groups x 2 col-groups) = 128 rows x 128 cols,
// sweeping all 8192 codes in 64 tiles. Per wave: A = 32 rows x 256 k resident in
// 64 VGPRs (converted from fp32 z with exact -2 scale); B fragments double-
// buffered in registers, loaded straight from L2-resident codebook. K-loop has
// zero LDS traffic and zero __syncthreads -> per-wave vmcnt only (AITER-style).
// score = esq - 2*dot comes directly out of the MFMA (C initialized with esq).
__global__ __launch_bounds__(512, 2)
void vq_mfma(const float* __restrict__ z, const __bf16* __restrict__ cbb,
             const float* __restrict__ esq, int* __restrict__ pI) {
    __shared__ float RedV[128][2];
    __shared__ int   RedI[128][2];

    const int rowbase = blockIdx.x * 128;
    const int tid = threadIdx.x;
    const int w = tid >> 6, l = tid & 63;
    const int rh = w >> 1, ch = w & 1;   // 4 row-groups x 2 col-groups
    const int lm = l & 15, lq = l >> 4;

    // ---- A prologue: 32 rows x 256 k per wave -> 16 bf16x8 frags (-2*z) ----
    bf16x8 Af[2][8];   // [row-seg][k-chunk]
    {
        const float* zp = z + (size_t)(rowbase + rh * 32 + lm) * DDIM + lq * 8;
#pragma unroll
        for (int s = 0; s < 2; ++s)
#pragma unroll
            for (int kc = 0; kc < 8; ++kc) {
                const float4 f0 = *(const float4*)(zp + s * 16 * DDIM + kc * 32);
                const float4 f1 = *(const float4*)(zp + s * 16 * DDIM + kc * 32 + 4);
                bf16x8 v;
                v[0] = (__bf16)(-2.f * f0.x); v[1] = (__bf16)(-2.f * f0.y);
                v[2] = (__bf16)(-2.f * f0.z); v[3] = (__bf16)(-2.f * f0.w);
                v[4] = (__bf16)(-2.f * f1.x); v[5] = (__bf16)(-2.f * f1.y);
                v[6] = (__bf16)(-2.f * f1.z); v[7] = (__bf16)(-2.f * f1.w);
                Af[s][kc] = v;
            }
    }

    // per-lane loop-invariant B offset per col-frag (elements)
    int voff[4];
#pragma unroll
    for (int fc = 0; fc < 4; ++fc)
        voff[fc] = (ch * 64 + fc * 16 + lm) * DDIM + lq * 8;

    // B chunk 0 + esq tile 0
    bf16x8 Bc[4], Bn[4];
#pragma unroll
    for (int fc = 0; fc < 4; ++fc) Bc[fc] = *(const bf16x8*)(cbb + voff[fc]);
    float evc[4], evn[4];
#pragma unroll
    for (int fc = 0; fc < 4; ++fc) evc[fc] = esq[ch * 64 + fc * 16 + lm];

    float bestV[8];
    int   bestI[8];
#pragma unroll
    for (int s = 0; s < 8; ++s) { bestV[s] = FLT_MAX; bestI[s] = 0; }

    for (int t = 0; t < NTILE; ++t) {
        f32x4 acc[2][4];
#pragma unroll
        for (int s = 0; s < 2; ++s)
#pragma unroll
            for (int fc = 0; fc < 4; ++fc) {
                const float e = evc[fc];
                acc[s][fc] = (f32x4){e, e, e, e};
            }
        {   // prefetch next tile's esq (unused garbage-free wrap at t=63)
            const int tn = (t + 1) & (NTILE - 1);
#pragma unroll
            for (int fc = 0; fc < 4; ++fc)
                evn[fc] = esq[tn * CT + ch * 64 + fc * 16 + lm];
        }

#pragma unroll
        for (int c = 0; c < NCH; ++c) {
            const int in = t * NCH + c + 1;           // next linear chunk
            if (in < NCHUNKS) {
                const size_t u = ((size_t)(in >> 3) << 15) + (size_t)((in & 7) << 5);
#pragma unroll
                for (int fc = 0; fc < 4; ++fc)
                    Bn[fc] = *(const bf16x8*)(cbb + u + voff[fc]);
            }
#pragma unroll
            for (int s = 0; s < 2; ++s)
#pragma unroll
                for (int fc = 0; fc < 4; ++fc)
                    acc[s][fc] = __builtin_amdgcn_mfma_f32_16x16x32_bf16(
                        Af[s][c], Bc[fc], acc[s][fc], 0, 0, 0);
#pragma unroll
            for (int fc = 0; fc < 4; ++fc) Bc[fc] = Bn[fc];
        }

        // epilogue: fused argmin (strict < : first-index tiebreak; tiles ascend)
#pragma unroll
        for (int s = 0; s < 2; ++s)
#pragma unroll
            for (int fc = 0; fc < 4; ++fc) {
                const int colI = t * CT + ch * 64 + fc * 16 + lm;
#pragma unroll
                for (int i = 0; i < 4; ++i) {
                    const float sc = acc[s][fc][i];
                    const int slot = s * 4 + i;
                    if (sc < bestV[slot]) { bestV[slot] = sc; bestI[slot] = colI; }
                }
            }
#pragma unroll
        for (int fc = 0; fc < 4; ++fc) evc[fc] = evn[fc];
    }

    // cross-lane argmin over the 16 col-lanes (lane bits 0..3 = lm)
#pragma unroll
    for (int s = 0; s < 8; ++s) {
#pragma unroll
        for (int m = 1; m < 16; m <<= 1) {
            const float v2 = __shfl_xor(bestV[s], m);
            const int   i2 = __shfl_xor(bestI[s], m);
            if (v2 < bestV[s] || (v2 == bestV[s] && i2 < bestI[s])) {
                bestV[s] = v2; bestI[s] = i2;
            }
        }
    }
    if (lm == 0) {
#pragma unroll
        for (int s = 0; s < 8; ++s) {
            const int rl = rh * 32 + (s >> 2) * 16 + lq * 4 + (s & 3);
            RedV[rl][ch] = bestV[s]; RedI[rl][ch] = bestI[s];
        }
    }
    __syncthreads();
    if (tid < 128) {  // combine the two col-halves; tie -> smaller index
        float v = RedV[tid][0]; int bi = RedI[tid][0];
        const float v2 = RedV[tid][1]; const int i2 = RedI[tid][1];
        if (v2 < v || (v2 == v && i2 < bi)) { v = v2; bi = i2; }
        pI[rowbase + tid] = bi;
    }
}

// ---- kernel C: gather (fp32), STE out, loss via device-scope last-block ----
__global__ __launch_bounds__(256)
void vq_finalize(const float* __restrict__ z, const float* __restrict__ cb,
                 const int* __restrict__ pI, float* __restrict__ out,
                 float* __restrict__ lossAcc, unsigned* __restrict__ counter) {
    __shared__ float sSum[4];
    const int tid = threadIdx.x;
    const int rw = tid >> 6, lane = tid & 63;
    const int row = blockIdx.x * 4 + rw;
    const int idx = pI[row];

    const float4 zv = *(const float4*)(z  + (size_t)row * DDIM + lane * 4);
    const float4 ev = *(const float4*)(cb + (size_t)idx * DDIM + lane * 4);
    float4 d, o;
    d.x = ev.x - zv.x; d.y = ev.y - zv.y; d.z = ev.z - zv.z; d.w = ev.w - zv.w;
    o.x = zv.x + d.x;  o.y = zv.y + d.y;  o.z = zv.z + d.z;  o.w = zv.w + d.w;
    *(float4*)(out + (size_t)row * DDIM + lane * 4) = o;

    float s = d.x * d.x + d.y * d.y + d.z * d.z + d.w * d.w;
    for (int off = 32; off > 0; off >>= 1) s += __shfl_down(s, off);
    if (lane == 0) sSum[rw] = s;
    __syncthreads();
    if (tid == 0) {
        atomicAdd(lossAcc, sSum[0] + sSum[1] + sSum[2] + sSum[3]);
        __threadfence();                       // order add before counter bump
        const unsigned done = atomicAdd(counter, 1u);
        if (done == gridDim.x - 1) {           // last block: all adds visible
            const float tot = atomicAdd(lossAcc, 0.f);  // coherent read
            out[(size_t)NROWS * DDIM] = tot * (1.25f / (float)((size_t)NROWS * DDIM));
        }
    }
}

extern "C" void kernel_launch(void* const* d_in, const int* in_sizes, int n_in,
                              void* d_out, int out_size, void* d_ws, size_t ws_size,
                              hipStream_t stream) {
    const float* z  = (const float*)d_in[0];
    const float* cb = (const float*)d_in[1];
    float* out = (float*)d_out;

    // bf16 codebook staged at the head of d_out (4 MB; fully overwritten later)
    __bf16* cbf = (__bf16*)d_out;

    // workspace carve (~170 KB)
    float*    esq     = (float*)d_ws;                 // 8192
    int*      pI      = (int*)(esq + NCODES);         // 32768
    float*    lossAcc = (float*)(pI + NROWS);         // 1
    unsigned* counter = (unsigned*)(lossAcc + 1);     // 1

    hipMemsetAsync(lossAcc, 0, 8, stream);            // zero loss accumulator + counter
    cvt_cb<<<NCODES * DDIM / 8 / 256, 256, 0, stream>>>(cb, cbf, esq);
    vq_mfma<<<NROWS / 128, 512, 0, stream>>>(z, cbf, esq, pI);
    vq_finalize<<<NROWS / 4, 256, 0, stream>>>(z, cb, pI, out, lossAcc, counter);
}

// Round 7
// 569.603 us; speedup vs baseline: 1.4275x; 1.4275x over previous
//
#include <hip/hip_runtime.h>
#include <cfloat>

#define NROWS  32768
#define NCODES 8192
#define DDIM   256
#define KG     2                // code-split: 2 blocks per row-tile -> grid 512 = 2 blocks/CU
#define CPB    (NCODES / KG)    // 4096 codes per block
#define CT     128              // codes per tile
#define TPB    (CPB / CT)       // 32 tiles per block
#define SPT    4                // stages per tile (64 k each)
#define NSTG   (TPB * SPT)      // 128 stages

typedef __attribute__((ext_vector_type(8))) __bf16 bf16x8;
typedef __attribute__((ext_vector_type(4))) float  f32x4;

// ---- kernel A: codebook fp32 -> bf16 + fused esq ----
__global__ __launch_bounds__(256)
void cvt_cb(const float* __restrict__ cb, __bf16* __restrict__ cbb,
            float* __restrict__ esq) {
    const size_t i = (size_t)(blockIdx.x * 256 + threadIdx.x) * 8;
    const float4 f0 = *(const float4*)(cb + i);
    const float4 f1 = *(const float4*)(cb + i + 4);
    bf16x8 v;
    v[0] = (__bf16)f0.x; v[1] = (__bf16)f0.y; v[2] = (__bf16)f0.z; v[3] = (__bf16)f0.w;
    v[4] = (__bf16)f1.x; v[5] = (__bf16)f1.y; v[6] = (__bf16)f1.z; v[7] = (__bf16)f1.w;
    *(bf16x8*)(cbb + i) = v;
    float s = f0.x * f0.x + f0.y * f0.y + f0.z * f0.z + f0.w * f0.w
            + f1.x * f1.x + f1.y * f1.y + f1.z * f1.z + f1.w * f1.w;
    for (int o = 16; o > 0; o >>= 1) s += __shfl_down(s, o, 32);
    if ((threadIdx.x & 31) == 0) esq[i >> 8] = s;
}

// ---- kernel B: A-in-registers + B via LDS dbuf (hybrid of R5/R6 winners) ----
// Block: 256 thr / 4 waves (2x2) = 128 rows x 128 cols; sweeps 4096 codes
// (KG=2 split; grid 512 -> 2 blocks/CU so one block's barrier drain is
// covered by the other block's MFMAs — m97 mechanism).
// A: 64 rows x 256 k per wave resident in regs (-2*z, exact scale).
// B: 128-code x 64-k stages (16 KB) via global_load_lds, double-buffered;
// loads issued at stage start get a full ~1242-cyc MFMA window before the
// barrier's vmcnt drain. score = esq - 2*dot directly from MFMA (C=esq).
__global__ __launch_bounds__(256, 2)
void vq_mfma(const float* __restrict__ z, const __bf16* __restrict__ cbb,
             const float* __restrict__ esq,
             float* __restrict__ pV, int* __restrict__ pI) {
    __shared__ __align__(16) __bf16 Bb[2][16 * 512];   // 2 x 16 KB
    __shared__ float RedV[128][2];
    __shared__ int   RedI[128][2];

    const int rowbase  = (blockIdx.x >> 1) * 128;
    const int kg       = blockIdx.x & 1;
    const int codebase = kg * CPB;

    const int tid = threadIdx.x;
    const int w = tid >> 6, l = tid & 63;
    const int rh = w >> 1, ch = w & 1;     // 2x2 wave grid: 64-row x 64-col tiles
    const int lm = l & 15, lq = l >> 4;
    const int loff = lm * DDIM + lq * 8;   // per-lane element offset in a 16-row seg

    // ---- stage 0 B loads first (overlap with A fp32 reads below) ----
#pragma unroll
    for (int j = 0; j < 4; ++j) {
        const int r = w * 4 + j, c2 = r >> 3, g = r & 7;
        __builtin_amdgcn_global_load_lds(
            (const __attribute__((address_space(1))) void*)
                (cbb + (size_t)(codebase + g * 16) * DDIM + c2 * 32 + loff),
            (__attribute__((address_space(3))) void*)&Bb[0][r * 512], 16, 0, 0);
    }

    // ---- A prologue: 64 rows x 256 k -> 32 bf16x8 frags (-2*z) ----
    bf16x8 Af[4][8];   // [row-seg][k-chunk]
    {
        const float* zp = z + (size_t)(rowbase + rh * 64 + lm) * DDIM + lq * 8;
#pragma unroll
        for (int s = 0; s < 4; ++s)
#pragma unroll
            for (int kc = 0; kc < 8; ++kc) {
                const float4 f0 = *(const float4*)(zp + s * 16 * DDIM + kc * 32);
                const float4 f1 = *(const float4*)(zp + s * 16 * DDIM + kc * 32 + 4);
                bf16x8 v;
                v[0] = (__bf16)(-2.f * f0.x); v[1] = (__bf16)(-2.f * f0.y);
                v[2] = (__bf16)(-2.f * f0.z); v[3] = (__bf16)(-2.f * f0.w);
                v[4] = (__bf16)(-2.f * f1.x); v[5] = (__bf16)(-2.f * f1.y);
                v[6] = (__bf16)(-2.f * f1.z); v[7] = (__bf16)(-2.f * f1.w);
                Af[s][kc] = v;
            }
    }

    // esq for tile 0 (ping-ponged across tiles)
    float evc[4], evn[4];
#pragma unroll
    for (int fc = 0; fc < 4; ++fc)
        evc[fc] = esq[codebase + ch * 64 + fc * 16 + lm];

    float bestV[16];
    int   bestI[16];
#pragma unroll
    for (int s = 0; s < 16; ++s) { bestV[s] = FLT_MAX; bestI[s] = 0; }

    __syncthreads();   // stage 0 staged (vmcnt drained by barrier semantics)

    int buf = 0;
    for (int t = 0; t < TPB; ++t) {
        f32x4 acc[4][4];
#pragma unroll
        for (int fr = 0; fr < 4; ++fr)
#pragma unroll
            for (int fc = 0; fc < 4; ++fc) {
                const float e = evc[fc];
                acc[fr][fc] = (f32x4){e, e, e, e};
            }
        {   // prefetch next tile's esq
            const int tn = (t + 1) & (TPB - 1);
#pragma unroll
            for (int fc = 0; fc < 4; ++fc)
                evn[fc] = esq[codebase + tn * CT + ch * 64 + fc * 16 + lm];
        }

#pragma unroll
        for (int ks = 0; ks < SPT; ++ks) {
            // issue next stage's loads into the other buffer FIRST
            const int ls = t * SPT + ks + 1;
            if (ls < NSTG) {
                const int nb = buf ^ 1;
                const __bf16* base = cbb + (size_t)(codebase + (ls >> 2) * CT) * DDIM
                                   + (ls & 3) * 64;
#pragma unroll
                for (int j = 0; j < 4; ++j) {
                    const int r = w * 4 + j, c2 = r >> 3, g = r & 7;
                    __builtin_amdgcn_global_load_lds(
                        (const __attribute__((address_space(1))) void*)
                            (base + (size_t)(g * 16) * DDIM + c2 * 32 + loff),
                        (__attribute__((address_space(3))) void*)&Bb[nb][r * 512], 16, 0, 0);
                }
            }
            // compute this stage: 2 k-chunks x 16 MFMAs (A from regs)
#pragma unroll
            for (int kk = 0; kk < 2; ++kk) {
                const int c = ks * 2 + kk;     // global k-chunk 0..7
                bf16x8 bfv[4];
#pragma unroll
                for (int fc = 0; fc < 4; ++fc)
                    bfv[fc] = *(const bf16x8*)&Bb[buf][(kk * 8 + ch * 4 + fc) * 512 + l * 8];
#pragma unroll
                for (int fr = 0; fr < 4; ++fr)
#pragma unroll
                    for (int fc = 0; fc < 4; ++fc)
                        acc[fr][fc] = __builtin_amdgcn_mfma_f32_16x16x32_bf16(
                            Af[fr][c], bfv[fc], acc[fr][fc], 0, 0, 0);
            }
            __syncthreads();   // loads had the full MFMA window to land
            buf ^= 1;
        }

        // epilogue: fused argmin (tiles ascend; fc ascend = cols ascend; strict <)
#pragma unroll
        for (int fr = 0; fr < 4; ++fr)
#pragma unroll
            for (int fc = 0; fc < 4; ++fc) {
                const int colI = codebase + t * CT + ch * 64 + fc * 16 + lm;
#pragma unroll
                for (int i = 0; i < 4; ++i) {
                    const float sc = acc[fr][fc][i];
                    const int slot = fr * 4 + i;
                    if (sc < bestV[slot]) { bestV[slot] = sc; bestI[slot] = colI; }
                }
            }
#pragma unroll
        for (int fc = 0; fc < 4; ++fc) evc[fc] = evn[fc];
    }

    // cross-lane argmin over the 16 col-lanes (lane bits 0..3 = lm)
#pragma unroll
    for (int s = 0; s < 16; ++s) {
#pragma unroll
        for (int m = 1; m < 16; m <<= 1) {
            const float v2 = __shfl_xor(bestV[s], m);
            const int   i2 = __shfl_xor(bestI[s], m);
            if (v2 < bestV[s] || (v2 == bestV[s] && i2 < bestI[s])) {
                bestV[s] = v2; bestI[s] = i2;
            }
        }
    }
    if (lm == 0) {
#pragma unroll
        for (int s = 0; s < 16; ++s) {   // row = rh*64 + fr*16 + lq*4 + i
            const int rl = rh * 64 + (s >> 2) * 16 + lq * 4 + (s & 3);
            RedV[rl][ch] = bestV[s]; RedI[rl][ch] = bestI[s];
        }
    }
    __syncthreads();
    if (tid < 128) {  // combine the two col-halves; tie -> smaller index
        float v = RedV[tid][0]; int bi = RedI[tid][0];
        const float v2 = RedV[tid][1]; const int i2 = RedI[tid][1];
        if (v2 < v || (v2 == v && i2 < bi)) { v = v2; bi = i2; }
        const int row = rowbase + tid;
        pV[row * KG + kg] = v; pI[row * KG + kg] = bi;
    }
}

// ---- kernel C: combine K-groups, gather (fp32), STE out, fused loss ----
__global__ __launch_bounds__(256)
void vq_finalize(const float* __restrict__ z, const float* __restrict__ cb,
                 const float* __restrict__ pV, const int* __restrict__ pI,
                 float* __restrict__ out,
                 float* __restrict__ lossAcc, unsigned* __restrict__ counter) {
    __shared__ float sSum[4];
    __shared__ int   sIdx[4];
    const int tid = threadIdx.x;
    const int rw = tid >> 6, lane = tid & 63;
    const int row = blockIdx.x * 4 + rw;

    if (lane == 0) {  // ascending kg = ascending index; strict < keeps first
        float v = pV[row * KG]; int bi = pI[row * KG];
        const float v2 = pV[row * KG + 1]; const int i2 = pI[row * KG + 1];
        if (v2 < v || (v2 == v && i2 < bi)) { v = v2; bi = i2; }
        sIdx[rw] = bi;
    }
    __syncthreads();
    const int idx = sIdx[rw];

    const float4 zv = *(const float4*)(z  + (size_t)row * DDIM + lane * 4);
    const float4 ev = *(const float4*)(cb + (size_t)idx * DDIM + lane * 4);
    float4 d, o;
    d.x = ev.x - zv.x; d.y = ev.y - zv.y; d.z = ev.z - zv.z; d.w = ev.w - zv.w;
    o.x = zv.x + d.x;  o.y = zv.y + d.y;  o.z = zv.z + d.z;  o.w = zv.w + d.w;
    *(float4*)(out + (size_t)row * DDIM + lane * 4) = o;

    float s = d.x * d.x + d.y * d.y + d.z * d.z + d.w * d.w;
    for (int off = 32; off > 0; off >>= 1) s += __shfl_down(s, off);
    if (lane == 0) sSum[rw] = s;
    __syncthreads();
    if (tid == 0) {
        atomicAdd(lossAcc, sSum[0] + sSum[1] + sSum[2] + sSum[3]);
        __threadfence();
        const unsigned done = atomicAdd(counter, 1u);
        if (done == gridDim.x - 1) {
            const float tot = atomicAdd(lossAcc, 0.f);  // coherent read
            out[(size_t)NROWS * DDIM] = tot * (1.25f / (float)((size_t)NROWS * DDIM));
        }
    }
}

extern "C" void kernel_launch(void* const* d_in, const int* in_sizes, int n_in,
                              void* d_out, int out_size, void* d_ws, size_t ws_size,
                              hipStream_t stream) {
    const float* z  = (const float*)d_in[0];
    const float* cb = (const float*)d_in[1];
    float* out = (float*)d_out;

    // bf16 codebook staged at head of d_out (4 MB; fully overwritten later)
    __bf16* cbf = (__bf16*)d_out;

    // workspace carve (~430 KB)
    float*    esq     = (float*)d_ws;                  // 8192
    float*    pV      = esq + NCODES;                  // 32768*2
    int*      pI      = (int*)(pV + NROWS * KG);       // 32768*2
    float*    lossAcc = (float*)(pI + NROWS * KG);     // 1
    unsigned* counter = (unsigned*)(lossAcc + 1);      // 1

    hipMemsetAsync(lossAcc, 0, 8, stream);
    cvt_cb<<<NCODES * DDIM / 8 / 256, 256, 0, stream>>>(cb, cbf, esq);
    vq_mfma<<<(NROWS / 128) * KG, 256, 0, stream>>>(z, cbf, esq, pV, pI);
    vq_finalize<<<NROWS / 4, 256, 0, stream>>>(z, cb, pV, pI, out, lossAcc, counter);
}

// Round 8
// 294.459 us; speedup vs baseline: 2.7613x; 1.9344x over previous
//
#include <hip/hip_runtime.h>
#include <cfloat>

#define NROWS  32768
#define NCODES 8192
#define DDIM   256
#define KG     2                 // code-split; grid = 128 row-tiles * 2 = 256 blocks
#define CPB    (NCODES / KG)     // 4096 codes per block
#define CT     128               // codes per tile/stage
#define TPB    (CPB / CT)        // 32 stages per block

typedef __attribute__((ext_vector_type(8))) __bf16 bf16x8;
typedef __attribute__((ext_vector_type(4))) float  f32x4;

// ---- kernel A: codebook fp32 -> bf16 + fused esq ----
__global__ __launch_bounds__(256)
void cvt_cb(const float* __restrict__ cb, __bf16* __restrict__ cbb,
            float* __restrict__ esq) {
    const size_t i = (size_t)(blockIdx.x * 256 + threadIdx.x) * 8;
    const float4 f0 = *(const float4*)(cb + i);
    const float4 f1 = *(const float4*)(cb + i + 4);
    bf16x8 v;
    v[0] = (__bf16)f0.x; v[1] = (__bf16)f0.y; v[2] = (__bf16)f0.z; v[3] = (__bf16)f0.w;
    v[4] = (__bf16)f1.x; v[5] = (__bf16)f1.y; v[6] = (__bf16)f1.z; v[7] = (__bf16)f1.w;
    *(bf16x8*)(cbb + i) = v;
    float s = f0.x * f0.x + f0.y * f0.y + f0.z * f0.z + f0.w * f0.w
            + f1.x * f1.x + f1.y * f1.y + f1.z * f1.z + f1.w * f1.w;
    for (int o = 16; o > 0; o >>= 1) s += __shfl_down(s, o, 32);
    if ((threadIdx.x & 31) == 0) esq[i >> 8] = s;
}

// ---- kernel B: A-in-regs, 256 rows/block, full-K 64KB stages ----
// 512 thr / 8 waves (4 row-groups x 2 col-groups); block = 256 rows x 4096
// codes (KG=2). A: 64 rows x 256 k per wave in VGPRs (-2*z exact). B: one
// 128-code x 256-k tile (64 KB) per stage via global_load_lds, double
// buffered; 1024 MFMAs (~5000 cyc) between barriers so the staging loads'
// latency and the barrier vmcnt drain are fully amortized (32 barriers
// total). 256-row reuse halves codebook re-read traffic vs round 5/7
// (512 MB total) — tests the L2/L3-bandwidth-plateau theory.
// score = esq - 2*dot directly from MFMA (C initialized with esq).
__global__ __launch_bounds__(512, 2)
void vq_mfma(const float* __restrict__ z, const __bf16* __restrict__ cbb,
             const float* __restrict__ esq,
             float* __restrict__ pV, int* __restrict__ pI) {
    __shared__ __align__(16) __bf16 Bb[2][64 * 512];   // 2 x 64 KB
    __shared__ float RedV[256][2];
    __shared__ int   RedI[256][2];

    const int rowbase  = (blockIdx.x >> 1) * 256;
    const int kg       = blockIdx.x & 1;
    const int codebase = kg * CPB;

    const int tid = threadIdx.x;
    const int w = tid >> 6, l = tid & 63;
    const int rh = w >> 1, ch = w & 1;     // 4 row-groups x 2 col-groups
    const int lm = l & 15, lq = l >> 4;
    const int loff = lm * DDIM + lq * 8;   // lane offset within a 16-row segment

    // ---- stage 0 B loads first (overlap with A conversion below) ----
    // wave w stages segment g=w (16 codes) for all 8 k-chunks; piece = c*8+g
#pragma unroll
    for (int j = 0; j < 8; ++j) {
        __builtin_amdgcn_global_load_lds(
            (const __attribute__((address_space(1))) void*)
                (cbb + (size_t)(codebase + w * 16) * DDIM + j * 32 + loff),
            (__attribute__((address_space(3))) void*)&Bb[0][(j * 8 + w) * 512], 16, 0, 0);
    }

    // ---- A prologue: 64 rows x 256 k per wave -> 32 bf16x8 frags (-2*z) ----
    bf16x8 Af[4][8];   // [row-seg fr][k-chunk]
    {
        const float* zp = z + (size_t)(rowbase + rh * 64 + lm) * DDIM + lq * 8;
#pragma unroll
        for (int s = 0; s < 4; ++s)
#pragma unroll
            for (int kc = 0; kc < 8; ++kc) {
                const float4 f0 = *(const float4*)(zp + s * 16 * DDIM + kc * 32);
                const float4 f1 = *(const float4*)(zp + s * 16 * DDIM + kc * 32 + 4);
                bf16x8 v;
                v[0] = (__bf16)(-2.f * f0.x); v[1] = (__bf16)(-2.f * f0.y);
                v[2] = (__bf16)(-2.f * f0.z); v[3] = (__bf16)(-2.f * f0.w);
                v[4] = (__bf16)(-2.f * f1.x); v[5] = (__bf16)(-2.f * f1.y);
                v[6] = (__bf16)(-2.f * f1.z); v[7] = (__bf16)(-2.f * f1.w);
                Af[s][kc] = v;
            }
    }

    // esq for tile 0 (ping-ponged across tiles)
    float evc[4], evn[4];
#pragma unroll
    for (int fc = 0; fc < 4; ++fc)
        evc[fc] = esq[codebase + ch * 64 + fc * 16 + lm];

    float bestV[16];
    int   bestI[16];
#pragma unroll
    for (int s = 0; s < 16; ++s) { bestV[s] = FLT_MAX; bestI[s] = 0; }

    __syncthreads();   // stage 0 staged

    int buf = 0;
    for (int t = 0; t < TPB; ++t) {
        // issue next stage's 64 KB into the other buffer FIRST (its reads
        // finished before the previous barrier, so overwrite is safe)
        if (t + 1 < TPB) {
            const int nb = buf ^ 1;
            const __bf16* base = cbb + (size_t)(codebase + (t + 1) * CT + w * 16) * DDIM;
#pragma unroll
            for (int j = 0; j < 8; ++j) {
                __builtin_amdgcn_global_load_lds(
                    (const __attribute__((address_space(1))) void*)(base + j * 32 + loff),
                    (__attribute__((address_space(3))) void*)&Bb[nb][(j * 8 + w) * 512], 16, 0, 0);
            }
        }
        {   // prefetch next tile's esq
            const int tn = (t + 1) & (TPB - 1);
#pragma unroll
            for (int fc = 0; fc < 4; ++fc)
                evn[fc] = esq[codebase + tn * CT + ch * 64 + fc * 16 + lm];
        }

        f32x4 acc[4][4];
#pragma unroll
        for (int fr = 0; fr < 4; ++fr)
#pragma unroll
            for (int fc = 0; fc < 4; ++fc) {
                const float e = evc[fc];
                acc[fr][fc] = (f32x4){e, e, e, e};
            }

        // compute the whole tile: 8 k-chunks x 16 MFMAs (A from regs)
#pragma unroll
        for (int c = 0; c < 8; ++c) {
            bf16x8 bfv[4];
#pragma unroll
            for (int fc = 0; fc < 4; ++fc)
                bfv[fc] = *(const bf16x8*)&Bb[buf][(c * 8 + ch * 4 + fc) * 512 + l * 8];
#pragma unroll
            for (int fr = 0; fr < 4; ++fr)
#pragma unroll
                for (int fc = 0; fc < 4; ++fc)
                    acc[fr][fc] = __builtin_amdgcn_mfma_f32_16x16x32_bf16(
                        Af[fr][c], bfv[fc], acc[fr][fc], 0, 0, 0);
        }

        // fused argmin (tiles ascend; fc ascend = cols ascend; strict <)
#pragma unroll
        for (int fr = 0; fr < 4; ++fr)
#pragma unroll
            for (int fc = 0; fc < 4; ++fc) {
                const int colI = codebase + t * CT + ch * 64 + fc * 16 + lm;
#pragma unroll
                for (int i = 0; i < 4; ++i) {
                    const float sc = acc[fr][fc][i];
                    const int slot = fr * 4 + i;
                    if (sc < bestV[slot]) { bestV[slot] = sc; bestI[slot] = colI; }
                }
            }
#pragma unroll
        for (int fc = 0; fc < 4; ++fc) evc[fc] = evn[fc];

        __syncthreads();   // next-stage loads landed during ~5000-cyc compute
        buf ^= 1;
    }

    // cross-lane argmin over the 16 col-lanes (lane bits 0..3 = lm)
#pragma unroll
    for (int s = 0; s < 16; ++s) {
#pragma unroll
        for (int m = 1; m < 16; m <<= 1) {
            const float v2 = __shfl_xor(bestV[s], m);
            const int   i2 = __shfl_xor(bestI[s], m);
            if (v2 < bestV[s] || (v2 == bestV[s] && i2 < bestI[s])) {
                bestV[s] = v2; bestI[s] = i2;
            }
        }
    }
    if (lm == 0) {
#pragma unroll
        for (int s = 0; s < 16; ++s) {   // row = rh*64 + fr*16 + lq*4 + i
            const int rl = rh * 64 + (s >> 2) * 16 + lq * 4 + (s & 3);
            RedV[rl][ch] = bestV[s]; RedI[rl][ch] = bestI[s];
        }
    }
    __syncthreads();
    if (tid < 256) {  // combine the two col-halves; tie -> smaller index
        float v = RedV[tid][0]; int bi = RedI[tid][0];
        const float v2 = RedV[tid][1]; const int i2 = RedI[tid][1];
        if (v2 < v || (v2 == v && i2 < bi)) { v = v2; bi = i2; }
        const int row = rowbase + tid;
        pV[row * KG + kg] = v; pI[row * KG + kg] = bi;
    }
}

// ---- kernel C: combine K-groups, gather (fp32), STE out, loss partials ----
// (atomic single-accumulator version regressed to 274 us in round 7 —
//  8192 same-address device atomics serialize; per-block partials are cheap)
__global__ __launch_bounds__(256)
void vq_finalize(const float* __restrict__ z, const float* __restrict__ cb,
                 const float* __restrict__ pV, const int* __restrict__ pI,
                 float* __restrict__ out, float* __restrict__ bsum) {
    __shared__ float sSum[4];
    __shared__ int   sIdx[4];
    const int tid = threadIdx.x;
    const int rw = tid >> 6, lane = tid & 63;
    const int row = blockIdx.x * 4 + rw;

    if (lane == 0) {  // ascending kg = ascending index; strict < keeps first
        float v = pV[row * KG]; int bi = pI[row * KG];
        const float v2 = pV[row * KG + 1]; const int i2 = pI[row * KG + 1];
        if (v2 < v || (v2 == v && i2 < bi)) { v = v2; bi = i2; }
        sIdx[rw] = bi;
    }
    __syncthreads();
    const int idx = sIdx[rw];

    const float4 zv = *(const float4*)(z  + (size_t)row * DDIM + lane * 4);
    const float4 ev = *(const float4*)(cb + (size_t)idx * DDIM + lane * 4);
    float4 d, o;
    d.x = ev.x - zv.x; d.y = ev.y - zv.y; d.z = ev.z - zv.z; d.w = ev.w - zv.w;
    o.x = zv.x + d.x;  o.y = zv.y + d.y;  o.z = zv.z + d.z;  o.w = zv.w + d.w;
    *(float4*)(out + (size_t)row * DDIM + lane * 4) = o;

    float s = d.x * d.x + d.y * d.y + d.z * d.z + d.w * d.w;
    for (int off = 32; off > 0; off >>= 1) s += __shfl_down(s, off);
    if (lane == 0) sSum[rw] = s;
    __syncthreads();
    if (tid == 0) bsum[blockIdx.x] = sSum[0] + sSum[1] + sSum[2] + sSum[3];
}

// ---- kernel D: loss ----
__global__ __launch_bounds__(256)
void loss_final(const float* __restrict__ bsum, float* __restrict__ out) {
    __shared__ float red[4];
    const int tid = threadIdx.x;
    float s = 0.f;
    for (int i = tid; i < NROWS / 4; i += 256) s += bsum[i];
    for (int off = 32; off > 0; off >>= 1) s += __shfl_down(s, off);
    const int wv = tid >> 6, lane = tid & 63;
    if (lane == 0) red[wv] = s;
    __syncthreads();
    if (tid == 0) {
        const float tot = red[0] + red[1] + red[2] + red[3];
        out[(size_t)NROWS * DDIM] = tot * (1.25f / (float)((size_t)NROWS * DDIM));
    }
}

extern "C" void kernel_launch(void* const* d_in, const int* in_sizes, int n_in,
                              void* d_out, int out_size, void* d_ws, size_t ws_size,
                              hipStream_t stream) {
    const float* z  = (const float*)d_in[0];
    const float* cb = (const float*)d_in[1];
    float* out = (float*)d_out;

    // bf16 codebook staged at head of d_out (4 MB; consumed by vq_mfma
    // before vq_finalize overwrites the region)
    __bf16* cbf = (__bf16*)d_out;

    // workspace carve (~580 KB)
    float* esq  = (float*)d_ws;                 // 8192
    float* pV   = esq + NCODES;                 // 32768*2
    int*   pI   = (int*)(pV + NROWS * KG);      // 32768*2
    float* bsum = (float*)(pI + NROWS * KG);    // 8192

    cvt_cb<<<NCODES * DDIM / 8 / 256, 256, 0, stream>>>(cb, cbf, esq);
    vq_mfma<<<(NROWS / 256) * KG, 512, 0, stream>>>(z, cbf, esq, pV, pI);
    vq_finalize<<<NROWS / 4, 256, 0, stream>>>(z, cb, pV, pI, out, bsum);
    loss_final<<<1, 256, 0, stream>>>(bsum, out);
}